// Round 2
// baseline (738.259 us; speedup 1.0000x reference)
//
#include <hip/hip_runtime.h>
#include <math.h>

#define BB 1024
#define TT 500
#define CC_ 64
#define KK 2000

__device__ __forceinline__ float lse2(float a, float b) {
    float m = fmaxf(a, b);
    float d = fminf(a, b) - m;
    return m + log1pf(__expf(d));
}

// Precompute P[k][0..7]:
//   P[k][s*2+o]   = sum_c A[k,c] * log_obs[c,s,o]   (a1 table)
//   P[k][4+s*2+u] = sum_c A[k,c] * log_t[c,s,u]     (a2c table)
__global__ __launch_bounds__(64) void precompute_P(
    const float* __restrict__ A,
    const float* __restrict__ trans_logits,
    const float* __restrict__ obs_logits,
    float* __restrict__ P)
{
    int k = blockIdx.x;
    int c = threadIdx.x;  // 0..63

    // log_obs[c][s][o] = obs[c,s,o] - LSE_o
    float ob[2][2];
#pragma unroll
    for (int s = 0; s < 2; ++s) {
        float o0 = obs_logits[c * 4 + s * 2 + 0];
        float o1 = obs_logits[c * 4 + s * 2 + 1];
        float l = lse2(o0, o1);
        ob[s][0] = o0 - l;
        ob[s][1] = o1 - l;
    }
    // log_t[c][s][u] = trans[c,s,u] - LSE over s (axis=1)
    float lt[2][2];
    {
        float t00 = trans_logits[c * 4 + 0];
        float t01 = trans_logits[c * 4 + 1];
        float t10 = trans_logits[c * 4 + 2];
        float t11 = trans_logits[c * 4 + 3];
        float l0 = lse2(t00, t10);  // over s, u=0
        float l1 = lse2(t01, t11);  // over s, u=1
        lt[0][0] = t00 - l0; lt[0][1] = t01 - l1;
        lt[1][0] = t10 - l0; lt[1][1] = t11 - l1;
    }

    float a = A[k * CC_ + c];
    float v[8];
    v[0] = a * ob[0][0]; v[1] = a * ob[0][1];
    v[2] = a * ob[1][0]; v[3] = a * ob[1][1];
    v[4] = a * lt[0][0]; v[5] = a * lt[0][1];
    v[6] = a * lt[1][0]; v[7] = a * lt[1][1];

#pragma unroll
    for (int i = 0; i < 8; ++i) {
#pragma unroll
        for (int m = 1; m < 64; m <<= 1) v[i] += __shfl_xor(v[i], m, 64);
    }
    if (c == 0) {
#pragma unroll
        for (int i = 0; i < 8; ++i) P[k * 8 + i] = v[i];
    }
}

// One wave per batch element. Lane c holds log_alpha[b,c,0..1] in registers.
// 1-step software pipeline: loads for t+1 issue before step t's compute so
// L2 latency (~200cy) hides under the shuffle/LSE dependency chain.
__global__ __launch_bounds__(64) void bkt_main(
    const int* __restrict__ corr,
    const int* __restrict__ kc,
    const float* __restrict__ A,
    const float* __restrict__ init_logits,
    const float* __restrict__ P,
    float* __restrict__ out)
{
    int b = blockIdx.x;
    int c = threadIdx.x;  // chain index 0..63

    float la0, la1;
    {
        float i0 = init_logits[c * 2 + 0];
        float i1 = init_logits[c * 2 + 1];
        float l = lse2(i0, i1);
        la0 = i0 - l;
        la1 = i1 - l;
    }

    const int* kcb = kc + b * TT;
    const int* cb  = corr + b * TT;
    float2* ob     = (float2*)(out + b * TT * 2);

    // prologue: load step 0
    int y = cb[0];
    float cc, p0, p1, p2, p3, q00, q01, q10, q11;
    {
        int k = kcb[0];
        cc = A[k * CC_ + c];
        const float* Pr = P + k * 8;
        p0 = Pr[0]; p1 = Pr[1]; p2 = Pr[2]; p3 = Pr[3];
        q00 = Pr[4]; q01 = Pr[5]; q10 = Pr[6]; q11 = Pr[7];
    }

    for (int t = 0; t < TT; ++t) {
        // ---- prefetch t+1 (independent of the serial chain) ----
        int yn = 0;
        float ccn = 0.f, n0 = 0.f, n1 = 0.f, n2 = 0.f, n3 = 0.f,
              n4 = 0.f, n5 = 0.f, n6 = 0.f, n7 = 0.f;
        if (t + 1 < TT) {
            int kn = kcb[t + 1];
            yn = cb[t + 1];
            ccn = A[kn * CC_ + c];
            const float* Pn = P + kn * 8;
            n0 = Pn[0]; n1 = Pn[1]; n2 = Pn[2]; n3 = Pn[3];
            n4 = Pn[4]; n5 = Pn[5]; n6 = Pn[6]; n7 = Pn[7];
        }

        // ---- a2[s] = sum_c cc * log_alpha[c,s] (the only live reduction) ----
        float r0 = cc * la0;
        float r1 = cc * la1;
#pragma unroll
        for (int m = 1; m < 64; m <<= 1) {
            r0 += __shfl_xor(r0, m, 64);
            r1 += __shfl_xor(r1, m, 64);
        }

        // predictive log-prob over outputs
        float lo_o0 = lse2(p0 + r0, p2 + r1);
        float lo_o1 = lse2(p1 + r0, p3 + r1);
        float lz = lse2(lo_o0, lo_o1);

        // state update: w[u] = a1[u][y] + a2[u]; a3[s] = LSE_u(w[u] + a2c[s][u])
        float w0 = (y == 0 ? p0 : p1) + r0;
        float w1 = (y == 0 ? p2 : p3) + r1;
        float a30 = lse2(w0 + q00, w1 + q01);
        float a31 = lse2(w0 + q10, w1 + q11);

        la0 = (1.0f - cc) * la0 + cc * a30;
        la1 = (1.0f - cc) * la1 + cc * a31;

        if (c == 0) {
            ob[t] = make_float2(lo_o0 - lz, lo_o1 - lz);
        }

        // ---- rotate pipeline ----
        y = yn; cc = ccn;
        p0 = n0; p1 = n1; p2 = n2; p3 = n3;
        q00 = n4; q01 = n5; q10 = n6; q11 = n7;
    }
}

extern "C" void kernel_launch(void* const* d_in, const int* in_sizes, int n_in,
                              void* d_out, int out_size, void* d_ws, size_t ws_size,
                              hipStream_t stream) {
    const int* corr   = (const int*)d_in[0];
    const int* kc     = (const int*)d_in[1];
    const float* A    = (const float*)d_in[2];
    const float* trans = (const float*)d_in[3];
    const float* obs  = (const float*)d_in[4];
    const float* init = (const float*)d_in[5];
    float* out = (float*)d_out;

    float* P = (float*)d_ws;  // K*8 floats = 64 KB

    precompute_P<<<KK, 64, 0, stream>>>(A, trans, obs, P);
    bkt_main<<<BB, 64, 0, stream>>>(corr, kc, A, init, P, out);
}

// Round 3
// 128.411 us; speedup vs baseline: 5.7492x; 5.7492x over previous
//
#include <hip/hip_runtime.h>
#include <math.h>

#define BB 1024
#define TT 500
#define CC_ 64
#define KK 2000

#define LOG2E 1.44269504088896340736f
#define LN2   0.69314718055994530942f

// ---- fast hardware exp2/log2 (v_exp_f32 / v_log_f32) ----
#if __has_builtin(__builtin_amdgcn_exp2f)
__device__ __forceinline__ float fast_exp2(float x) { return __builtin_amdgcn_exp2f(x); }
#else
__device__ __forceinline__ float fast_exp2(float x) { return exp2f(x); }
#endif
#if __has_builtin(__builtin_amdgcn_logf)
__device__ __forceinline__ float fast_log2(float x) { return __builtin_amdgcn_logf(x); }
#else
__device__ __forceinline__ float fast_log2(float x) { return log2f(x); }
#endif

// log-sum-exp in base-2 domain: log2(2^a + 2^b)
__device__ __forceinline__ float lse2_2(float a, float b) {
    float m = fmaxf(a, b);
    float d = fminf(a, b) - m;              // <= 0
    return m + fast_log2(1.0f + fast_exp2(d));
}

// ---- DPP wave-64 sum reduction (VALU pipe, no LDS) ----
// row_shr:1/2/4/8 then row_bcast15 (rows 1,3) + row_bcast31 (rows 2,3).
// Lane 63 ends with the full 64-lane sum.
template<int CTRL, int RM, int BM>
__device__ __forceinline__ float dpp_add(float x) {
    int s = __builtin_amdgcn_update_dpp(0, __float_as_int(x), CTRL, RM, BM, true);
    return x + __int_as_float(s);
}
__device__ __forceinline__ float wave_sum63(float x) {
    x = dpp_add<0x111, 0xf, 0xf>(x);  // row_shr:1
    x = dpp_add<0x112, 0xf, 0xf>(x);  // row_shr:2
    x = dpp_add<0x114, 0xf, 0xf>(x);  // row_shr:4
    x = dpp_add<0x118, 0xf, 0xf>(x);  // row_shr:8  -> lane 15 of each row = row sum
    x = dpp_add<0x142, 0xa, 0xf>(x);  // row_bcast15, rows 1&3 -> lane31=r0+r1, lane63=r2+r3
    x = dpp_add<0x143, 0xc, 0xf>(x);  // row_bcast31, rows 2&3 -> lane63=total
    return x;
}
__device__ __forceinline__ float bcast63(float x) {
    return __int_as_float(__builtin_amdgcn_readlane(__float_as_int(x), 63));
}

// Precompute P[k][0..7] in LOG2 units:
//   P[k][s*2+o]   = sum_c A[k,c] * log2_softmax(obs)[c,s,o]
//   P[k][4+s*2+u] = sum_c A[k,c] * log2_softmax_ax1(trans)[c,s,u]
__global__ __launch_bounds__(64) void precompute_P(
    const float* __restrict__ A,
    const float* __restrict__ trans_logits,
    const float* __restrict__ obs_logits,
    float* __restrict__ P)
{
    int k = blockIdx.x;
    int c = threadIdx.x;  // 0..63

    float ob[2][2];
#pragma unroll
    for (int s = 0; s < 2; ++s) {
        float o0 = obs_logits[c * 4 + s * 2 + 0] * LOG2E;
        float o1 = obs_logits[c * 4 + s * 2 + 1] * LOG2E;
        float l = lse2_2(o0, o1);
        ob[s][0] = o0 - l;
        ob[s][1] = o1 - l;
    }
    float lt[2][2];
    {
        float t00 = trans_logits[c * 4 + 0] * LOG2E;
        float t01 = trans_logits[c * 4 + 1] * LOG2E;
        float t10 = trans_logits[c * 4 + 2] * LOG2E;
        float t11 = trans_logits[c * 4 + 3] * LOG2E;
        float l0 = lse2_2(t00, t10);  // normalize over s (axis=1), u=0
        float l1 = lse2_2(t01, t11);  // u=1
        lt[0][0] = t00 - l0; lt[0][1] = t01 - l1;
        lt[1][0] = t10 - l0; lt[1][1] = t11 - l1;
    }

    float a = A[k * CC_ + c];
    float v[8];
    v[0] = a * ob[0][0]; v[1] = a * ob[0][1];
    v[2] = a * ob[1][0]; v[3] = a * ob[1][1];
    v[4] = a * lt[0][0]; v[5] = a * lt[0][1];
    v[6] = a * lt[1][0]; v[7] = a * lt[1][1];

#pragma unroll
    for (int i = 0; i < 8; ++i) v[i] = wave_sum63(v[i]);
    if (c == 63) {
#pragma unroll
        for (int i = 0; i < 8; ++i) P[k * 8 + i] = v[i];
    }
}

// Serial forward pass. One wave per batch element; lane c holds
// log2_alpha[b,c,0..1] in 2 VGPRs for the whole scan. Per step, only the
// state reduction r[s] = sum_c A[k,c]*la[c,s] is computed here (DPP reduce);
// lane 63 stores (r0,r1) to d_out and finish_py turns them into the output
// log-softmax fully in parallel afterwards.
__global__ __launch_bounds__(64) void bkt_main(
    const int* __restrict__ corr,
    const int* __restrict__ kc,
    const float* __restrict__ A,
    const float* __restrict__ init_logits,
    const float* __restrict__ P,
    float* __restrict__ out)
{
    int b = blockIdx.x;
    int c = threadIdx.x;

    float la0, la1;
    {
        float i0 = init_logits[c * 2 + 0] * LOG2E;
        float i1 = init_logits[c * 2 + 1] * LOG2E;
        float l = lse2_2(i0, i1);
        la0 = i0 - l;
        la1 = i1 - l;
    }

    const int* kcb = kc + b * TT;
    const int* cb  = corr + b * TT;
    float2* outb   = (float2*)(out + (size_t)b * TT * 2);

    // pipeline prologue: k/y for t=0,1; A-row & P-row for t=0
    int k1 = kcb[0], y0 = cb[0];
    int k2 = kcb[1], y1 = cb[1];
    float cc0 = A[k1 * CC_ + c];
    float4 pa0 = *(const float4*)(P + k1 * 8);
    float4 pb0 = *(const float4*)(P + k1 * 8 + 4);
    k1 = k2;

    for (int t = 0; t < TT; ++t) {
        // ---- prefetch: k/y at depth 2, A/P rows at depth 1 ----
        int tn = (t + 2 < TT) ? (t + 2) : (TT - 1);
        int kn = kcb[tn];
        int yn = cb[tn];
        float cc1  = A[k1 * CC_ + c];
        float4 pa1 = *(const float4*)(P + k1 * 8);
        float4 pb1 = *(const float4*)(P + k1 * 8 + 4);

        // ---- the live reduction: r[s] = sum_c cc*la[c,s] ----
        float x0 = wave_sum63(cc0 * la0);
        float x1 = wave_sum63(cc0 * la1);
        if (c == 63) outb[t] = make_float2(x0, x1);  // raw a2 for finish_py
        float r0 = bcast63(x0);
        float r1 = bcast63(x1);

        // ---- state update: w[u]=a1[u][y]+r[u]; a3[s]=LSE2_u(w[u]+q[s][u]) ----
        float w0 = ((y0 == 0) ? pa0.x : pa0.y) + r0;
        float w1 = ((y0 == 0) ? pa0.z : pa0.w) + r1;
        float a30 = lse2_2(w0 + pb0.x, w1 + pb0.y);
        float a31 = lse2_2(w0 + pb0.z, w1 + pb0.w);
        la0 += cc0 * (a30 - la0);   // (1-cc)*la + cc*a3
        la1 += cc0 * (a31 - la1);

        // ---- rotate pipeline ----
        cc0 = cc1; pa0 = pa1; pb0 = pb1;
        y0 = y1; y1 = yn; k1 = kn;
    }
}

// Fully parallel epilogue: turn stored (r0,r1) into log-softmax'd output
// (in natural-log units), in place in d_out.
__global__ __launch_bounds__(256) void finish_py(
    const int* __restrict__ kc,
    const float* __restrict__ P,
    float* __restrict__ out)
{
    int i = blockIdx.x * 256 + threadIdx.x;  // i = b*TT + t
    if (i >= BB * TT) return;
    int k = kc[i];
    float2 r = ((const float2*)out)[i];
    float4 pa = *(const float4*)(P + k * 8);
    float lo0 = lse2_2(pa.x + r.x, pa.z + r.y);  // log2 p(y=0)
    float lo1 = lse2_2(pa.y + r.x, pa.w + r.y);  // log2 p(y=1)
    float lz  = lse2_2(lo0, lo1);
    ((float2*)out)[i] = make_float2((lo0 - lz) * LN2, (lo1 - lz) * LN2);
}

extern "C" void kernel_launch(void* const* d_in, const int* in_sizes, int n_in,
                              void* d_out, int out_size, void* d_ws, size_t ws_size,
                              hipStream_t stream) {
    const int* corr    = (const int*)d_in[0];
    const int* kc      = (const int*)d_in[1];
    const float* A     = (const float*)d_in[2];
    const float* trans = (const float*)d_in[3];
    const float* obs   = (const float*)d_in[4];
    const float* init  = (const float*)d_in[5];
    float* out = (float*)d_out;

    float* P = (float*)d_ws;  // K*8 floats = 64 KB (in log2 units)

    precompute_P<<<KK, 64, 0, stream>>>(A, trans, obs, P);
    bkt_main<<<BB, 64, 0, stream>>>(corr, kc, A, init, P, out);
    finish_py<<<(BB * TT + 255) / 256, 256, 0, stream>>>(kc, P, out);
}

// Round 4
// 103.608 us; speedup vs baseline: 7.1255x; 1.2394x over previous
//
#include <hip/hip_runtime.h>
#include <math.h>

#define BB 1024
#define TT 500
#define CC_ 64
#define KK 2000

#define LOG2E 1.44269504088896340736f
#define LN2   0.69314718055994530942f

// ---- fast hardware exp2/log2 (v_exp_f32 / v_log_f32) ----
#if __has_builtin(__builtin_amdgcn_exp2f)
__device__ __forceinline__ float fast_exp2(float x) { return __builtin_amdgcn_exp2f(x); }
#else
__device__ __forceinline__ float fast_exp2(float x) { return exp2f(x); }
#endif
#if __has_builtin(__builtin_amdgcn_logf)
__device__ __forceinline__ float fast_log2(float x) { return __builtin_amdgcn_logf(x); }
#else
__device__ __forceinline__ float fast_log2(float x) { return log2f(x); }
#endif

// max-guarded log2-sum-exp2 (used off the hot loop, where ranges are unknown)
__device__ __forceinline__ float lse2_2(float a, float b) {
    float m = fmaxf(a, b);
    float d = fminf(a, b) - m;              // <= 0
    return m + fast_log2(1.0f + fast_exp2(d));
}

// ---- DPP wave-64 sum reduction (VALU pipe, no LDS) ----
template<int CTRL, int RM, int BM>
__device__ __forceinline__ float dpp_add(float x) {
    int s = __builtin_amdgcn_update_dpp(0, __float_as_int(x), CTRL, RM, BM, true);
    return x + __int_as_float(s);
}
__device__ __forceinline__ float wave_sum63(float x) {
    x = dpp_add<0x111, 0xf, 0xf>(x);  // row_shr:1
    x = dpp_add<0x112, 0xf, 0xf>(x);  // row_shr:2
    x = dpp_add<0x114, 0xf, 0xf>(x);  // row_shr:4
    x = dpp_add<0x118, 0xf, 0xf>(x);  // row_shr:8  -> lane15 of each row = row sum
    x = dpp_add<0x142, 0xa, 0xf>(x);  // row_bcast15 (rows 1,3)
    x = dpp_add<0x143, 0xc, 0xf>(x);  // row_bcast31 (rows 2,3) -> lane63 = total
    return x;
}
__device__ __forceinline__ float bcast63(float x) {
    return __int_as_float(__builtin_amdgcn_readlane(__float_as_int(x), 63));
}

// Precompute P[k][0..7] in LOG2 units:
//   P[k][s*2+o]   = sum_c A[k,c] * log2_softmax(obs)[c,s,o]
//   P[k][4+s*2+u] = sum_c A[k,c] * log2_softmax_ax1(trans)[c,s,u]
__global__ __launch_bounds__(64) void precompute_P(
    const float* __restrict__ A,
    const float* __restrict__ trans_logits,
    const float* __restrict__ obs_logits,
    float* __restrict__ P)
{
    int k = blockIdx.x;
    int c = threadIdx.x;  // 0..63

    float ob[2][2];
#pragma unroll
    for (int s = 0; s < 2; ++s) {
        float o0 = obs_logits[c * 4 + s * 2 + 0] * LOG2E;
        float o1 = obs_logits[c * 4 + s * 2 + 1] * LOG2E;
        float l = lse2_2(o0, o1);
        ob[s][0] = o0 - l;
        ob[s][1] = o1 - l;
    }
    float lt[2][2];
    {
        float t00 = trans_logits[c * 4 + 0] * LOG2E;
        float t01 = trans_logits[c * 4 + 1] * LOG2E;
        float t10 = trans_logits[c * 4 + 2] * LOG2E;
        float t11 = trans_logits[c * 4 + 3] * LOG2E;
        float l0 = lse2_2(t00, t10);  // normalize over s (axis=1), u=0
        float l1 = lse2_2(t01, t11);  // u=1
        lt[0][0] = t00 - l0; lt[0][1] = t01 - l1;
        lt[1][0] = t10 - l0; lt[1][1] = t11 - l1;
    }

    float a = A[k * CC_ + c];
    float v[8];
    v[0] = a * ob[0][0]; v[1] = a * ob[0][1];
    v[2] = a * ob[1][0]; v[3] = a * ob[1][1];
    v[4] = a * lt[0][0]; v[5] = a * lt[0][1];
    v[6] = a * lt[1][0]; v[7] = a * lt[1][1];

#pragma unroll
    for (int i = 0; i < 8; ++i) v[i] = wave_sum63(v[i]);
    if (c == 63) {
#pragma unroll
        for (int i = 0; i < 8; ++i) P[k * 8 + i] = v[i];
    }
}

// Serial forward pass. One wave per batch element; lane c holds
// log2_alpha[b,c,0..1] in 2 VGPRs. Stage arrays (3-deep, compile-time
// indices in a x3-unrolled loop) rotate registers with zero movs; A/P
// prefetched 2 steps ahead, k/y 3 steps ahead. la is renormalized by -r0
// each step (uniform shift, output-invariant) so magnitudes stay small and
// the LSE needs no max-guard: a3 = log2(2^x0 + 2^x1) directly.
__global__ __launch_bounds__(64) void bkt_main(
    const int* __restrict__ corr,
    const int* __restrict__ kc,
    const float* __restrict__ A,
    const float* __restrict__ init_logits,
    const float* __restrict__ P,
    float* __restrict__ out)
{
    int b = blockIdx.x;
    int c = threadIdx.x;

    float la0, la1;
    {
        float i0 = init_logits[c * 2 + 0] * LOG2E;
        float i1 = init_logits[c * 2 + 1] * LOG2E;
        float l = lse2_2(i0, i1);
        la0 = i0 - l;
        la1 = i1 - l;
    }

    const int* kcb = kc + b * TT;
    const int* cb  = corr + b * TT;
    float2* outb   = (float2*)(out + (size_t)b * TT * 2);

    int kq[3], yq[3];
    kq[0] = kcb[0]; kq[1] = kcb[1]; kq[2] = kcb[2];
    yq[0] = cb[0];  yq[1] = cb[1];  yq[2] = cb[2];

    float  ccA[3];
    float4 pa[3], pb[3];
    ccA[0] = A[kq[0] * CC_ + c];
    pa[0]  = *(const float4*)(P + kq[0] * 8);
    pb[0]  = *(const float4*)(P + kq[0] * 8 + 4);
    ccA[1] = A[kq[1] * CC_ + c];
    pa[1]  = *(const float4*)(P + kq[1] * 8);
    pb[1]  = *(const float4*)(P + kq[1] * 8 + 4);

    // 501 = 3*167; the phantom step t=500 has clamped loads and a guarded store.
    for (int tt = 0; tt < 501; tt += 3) {
#pragma unroll
        for (int j = 0; j < 3; ++j) {
            int t = tt + j;
            // ---- prefetch A/P rows for t+2 into slot (j+2)%3 ----
            int kp2 = kq[(j + 2) % 3];
            ccA[(j + 2) % 3] = A[kp2 * CC_ + c];
            pa[(j + 2) % 3]  = *(const float4*)(P + kp2 * 8);
            pb[(j + 2) % 3]  = *(const float4*)(P + kp2 * 8 + 4);
            // ---- consume y, refill k/y slot j with t+3 ----
            int y = yq[j];
            int t3 = t + 3; if (t3 > TT - 1) t3 = TT - 1;
            kq[j] = kcb[t3];
            yq[j] = cb[t3];

            // ---- live reduction r[s] = sum_c cc*la[c,s] ----
            float cc = ccA[j];
            float x0 = wave_sum63(cc * la0);
            float x1 = wave_sum63(cc * la1);
            if (t < TT && c == 63) outb[t] = make_float2(x0, x1);
            float r0 = bcast63(x0);
            float r1 = bcast63(x1);

            // ---- state update (plain exp2/log2; renorm keeps ranges safe) ----
            float4 a1v = pa[j], qv = pb[j];
            float w0 = (y == 0 ? a1v.x : a1v.y) + r0;
            float w1 = (y == 0 ? a1v.z : a1v.w) + r1;
            float a30 = fast_log2(fast_exp2(w0 + qv.x) + fast_exp2(w1 + qv.y));
            float a31 = fast_log2(fast_exp2(w0 + qv.z) + fast_exp2(w1 + qv.w));
            // la = (1-cc)*la + cc*a3, then uniform shift by -r0 (output-invariant)
            la0 = la0 + cc * (a30 - la0) - r0;
            la1 = la1 + cc * (a31 - la1) - r0;
        }
    }
}

// Fully parallel epilogue: stored (r0,r1) -> log-softmax'd output (nat-log).
// Safe (max-guarded) LSE here; the uniform shift in r cancels in lz.
__global__ __launch_bounds__(256) void finish_py(
    const int* __restrict__ kc,
    const float* __restrict__ P,
    float* __restrict__ out)
{
    int i = blockIdx.x * 256 + threadIdx.x;  // i = b*TT + t
    if (i >= BB * TT) return;
    int k = kc[i];
    float2 r = ((const float2*)out)[i];
    float4 pa = *(const float4*)(P + k * 8);
    float lo0 = lse2_2(pa.x + r.x, pa.z + r.y);  // log2 p(y=0) (shifted)
    float lo1 = lse2_2(pa.y + r.x, pa.w + r.y);  // log2 p(y=1) (shifted)
    float lz  = lse2_2(lo0, lo1);
    ((float2*)out)[i] = make_float2((lo0 - lz) * LN2, (lo1 - lz) * LN2);
}

extern "C" void kernel_launch(void* const* d_in, const int* in_sizes, int n_in,
                              void* d_out, int out_size, void* d_ws, size_t ws_size,
                              hipStream_t stream) {
    const int* corr    = (const int*)d_in[0];
    const int* kc      = (const int*)d_in[1];
    const float* A     = (const float*)d_in[2];
    const float* trans = (const float*)d_in[3];
    const float* obs   = (const float*)d_in[4];
    const float* init  = (const float*)d_in[5];
    float* out = (float*)d_out;

    float* P = (float*)d_ws;  // K*8 floats = 64 KB (log2 units)

    precompute_P<<<KK, 64, 0, stream>>>(A, trans, obs, P);
    bkt_main<<<BB, 64, 0, stream>>>(corr, kc, A, init, P, out);
    finish_py<<<(BB * TT + 255) / 256, 256, 0, stream>>>(kc, P, out);
}

// Round 5
// 102.651 us; speedup vs baseline: 7.1919x; 1.0093x over previous
//
#include <hip/hip_runtime.h>
#include <math.h>

#define BB 1024
#define TT 500
#define CC_ 64
#define KK 2000

#define LOG2E 1.44269504088896340736f
#define LN2   0.69314718055994530942f

// ---- fast hardware exp2/log2 (v_exp_f32 / v_log_f32) ----
#if __has_builtin(__builtin_amdgcn_exp2f)
__device__ __forceinline__ float fast_exp2(float x) { return __builtin_amdgcn_exp2f(x); }
#else
__device__ __forceinline__ float fast_exp2(float x) { return exp2f(x); }
#endif
#if __has_builtin(__builtin_amdgcn_logf)
__device__ __forceinline__ float fast_log2(float x) { return __builtin_amdgcn_logf(x); }
#else
__device__ __forceinline__ float fast_log2(float x) { return log2f(x); }
#endif

// max-guarded log2-sum-exp2 (off the hot loop)
__device__ __forceinline__ float lse2_2(float a, float b) {
    float m = fmaxf(a, b);
    float d = fminf(a, b) - m;              // <= 0
    return m + fast_log2(1.0f + fast_exp2(d));
}

// ---- DPP wave-64 sum reduction (VALU pipe, no LDS) ----
template<int CTRL, int RM, int BM>
__device__ __forceinline__ float dpp_add(float x) {
    int s = __builtin_amdgcn_update_dpp(0, __float_as_int(x), CTRL, RM, BM, true);
    return x + __int_as_float(s);
}
__device__ __forceinline__ float wave_sum63(float x) {
    x = dpp_add<0x111, 0xf, 0xf>(x);  // row_shr:1
    x = dpp_add<0x112, 0xf, 0xf>(x);  // row_shr:2
    x = dpp_add<0x114, 0xf, 0xf>(x);  // row_shr:4
    x = dpp_add<0x118, 0xf, 0xf>(x);  // row_shr:8  -> lane15 of each row = row sum
    x = dpp_add<0x142, 0xa, 0xf>(x);  // row_bcast15 (rows 1,3)
    x = dpp_add<0x143, 0xc, 0xf>(x);  // row_bcast31 (rows 2,3) -> lane63 = total
    return x;
}
__device__ __forceinline__ float bcast63(float x) {
    return __int_as_float(__builtin_amdgcn_readlane(__float_as_int(x), 63));
}

// Precompute P[k][0..7] in LOG2 units:
//   P[k][s*2+o]   = sum_c A[k,c] * log2_softmax(obs)[c,s,o]
//   P[k][4+s*2+u] = sum_c A[k,c] * log2_softmax_ax1(trans)[c,s,u]
__global__ __launch_bounds__(64) void precompute_P(
    const float* __restrict__ A,
    const float* __restrict__ trans_logits,
    const float* __restrict__ obs_logits,
    float* __restrict__ P)
{
    int k = blockIdx.x;
    int c = threadIdx.x;  // 0..63

    float ob[2][2];
#pragma unroll
    for (int s = 0; s < 2; ++s) {
        float o0 = obs_logits[c * 4 + s * 2 + 0] * LOG2E;
        float o1 = obs_logits[c * 4 + s * 2 + 1] * LOG2E;
        float l = lse2_2(o0, o1);
        ob[s][0] = o0 - l;
        ob[s][1] = o1 - l;
    }
    float lt[2][2];
    {
        float t00 = trans_logits[c * 4 + 0] * LOG2E;
        float t01 = trans_logits[c * 4 + 1] * LOG2E;
        float t10 = trans_logits[c * 4 + 2] * LOG2E;
        float t11 = trans_logits[c * 4 + 3] * LOG2E;
        float l0 = lse2_2(t00, t10);  // normalize over s (axis=1), u=0
        float l1 = lse2_2(t01, t11);  // u=1
        lt[0][0] = t00 - l0; lt[0][1] = t01 - l1;
        lt[1][0] = t10 - l0; lt[1][1] = t11 - l1;
    }

    float a = A[k * CC_ + c];
    float v[8];
    v[0] = a * ob[0][0]; v[1] = a * ob[0][1];
    v[2] = a * ob[1][0]; v[3] = a * ob[1][1];
    v[4] = a * lt[0][0]; v[5] = a * lt[0][1];
    v[6] = a * lt[1][0]; v[7] = a * lt[1][1];

#pragma unroll
    for (int i = 0; i < 8; ++i) v[i] = wave_sum63(v[i]);
    if (c == 63) {
#pragma unroll
        for (int i = 0; i < 8; ++i) P[k * 8 + i] = v[i];
    }
}

// Serial forward pass. One wave per batch; lane c holds log2_alpha[c,0..1].
// ALL in-loop loads are forced onto the VMEM path (per-lane addresses via an
// opaque VGPR zero `z`): vmcnt is partially waitable, so the k/y ring (depth
// 8) and A/P ring (depth 4, issued 3 steps ahead) actually pipeline. SMEM
// s_loads are avoided entirely — their out-of-order completion forces
// lgkmcnt(0) drains that serialized the previous version.
__global__ __launch_bounds__(64) void bkt_main(
    const int* __restrict__ corr,
    const int* __restrict__ kc,
    const float* __restrict__ A,
    const float* __restrict__ init_logits,
    const float* __restrict__ P,
    float* __restrict__ out)
{
    int b = blockIdx.x;
    int c = threadIdx.x;

    int z;  // opaque zero in a VGPR (not volatile: hoists, never constant-folds)
    asm("v_mov_b32 %0, 0" : "=v"(z));

    float la0, la1;
    {
        float i0 = init_logits[c * 2 + 0] * LOG2E;
        float i1 = init_logits[c * 2 + 1] * LOG2E;
        float l = lse2_2(i0, i1);
        la0 = i0 - l;
        la1 = i1 - l;
    }

    const int* kcb = kc + b * TT;
    const int* cb  = corr + b * TT;
    float2* outb   = (float2*)(out + (size_t)b * TT * 2);

    // k/y ring, depth 8 (slot i holds step tt+i's values)
    int kq[8], yq[8];
#pragma unroll
    for (int i = 0; i < 8; ++i) {
        kq[i] = kcb[i + z];   // VGPR index -> global_load_dword (VMEM)
        yq[i] = cb[i + z];
    }
    // A/P ring, depth 4; prefill slots 0..2 (for t=0,1,2)
    float  ccq[4];
    float4 paq[4], pbq[4];
#pragma unroll
    for (int i = 0; i < 3; ++i) {
        ccq[i] = A[kq[i] * CC_ + c];
        paq[i] = *(const float4*)(P + kq[i] * 8);
        pbq[i] = *(const float4*)(P + kq[i] * 8 + 4);
    }

    // 504 = 8*63; steps 500..503 are phantoms (clamped loads, guarded store).
    for (int tt = 0; tt < 504; tt += 8) {
#pragma unroll
        for (int j = 0; j < 8; ++j) {
            int t = tt + j;
            // ---- refill k/y slot j with step t+8 ----
            int t8 = t + 8; if (t8 > TT - 1) t8 = TT - 1;
            int knew = kcb[t8 + z];
            int ynew = cb[t8 + z];
            // ---- prefetch A/P for step t+3 into AP slot (j+3)&3 ----
            int kp = kq[(j + 3) & 7];
            ccq[(j + 3) & 3] = A[kp * CC_ + c];
            paq[(j + 3) & 3] = *(const float4*)(P + kp * 8);
            pbq[(j + 3) & 3] = *(const float4*)(P + kp * 8 + 4);
            // ---- consume step t ----
            int y = yq[j];
            kq[j] = knew;
            yq[j] = ynew;
            float cc   = ccq[j & 3];
            float4 a1v = paq[j & 3];
            float4 qv  = pbq[j & 3];

            // live reduction r[s] = sum_c cc*la[c,s]
            float x0 = wave_sum63(cc * la0);
            float x1 = wave_sum63(cc * la1);
            if (t < TT && c == 63) outb[t] = make_float2(x0, x1);
            float r0 = bcast63(x0);
            float r1 = bcast63(x1);

            // state update (plain exp2/log2; renorm by -r0 keeps ranges safe)
            float w0 = (y == 0 ? a1v.x : a1v.y) + r0;
            float w1 = (y == 0 ? a1v.z : a1v.w) + r1;
            float a30 = fast_log2(fast_exp2(w0 + qv.x) + fast_exp2(w1 + qv.y));
            float a31 = fast_log2(fast_exp2(w0 + qv.z) + fast_exp2(w1 + qv.w));
            la0 = la0 + cc * (a30 - la0) - r0;
            la1 = la1 + cc * (a31 - la1) - r0;
        }
    }
}

// Fully parallel epilogue: stored (r0,r1) -> log-softmax'd output (nat-log).
__global__ __launch_bounds__(256) void finish_py(
    const int* __restrict__ kc,
    const float* __restrict__ P,
    float* __restrict__ out)
{
    int i = blockIdx.x * 256 + threadIdx.x;  // i = b*TT + t
    if (i >= BB * TT) return;
    int k = kc[i];
    float2 r = ((const float2*)out)[i];
    float4 pa = *(const float4*)(P + k * 8);
    float lo0 = lse2_2(pa.x + r.x, pa.z + r.y);  // log2 p(y=0) (shifted)
    float lo1 = lse2_2(pa.y + r.x, pa.w + r.y);  // log2 p(y=1) (shifted)
    float lz  = lse2_2(lo0, lo1);
    ((float2*)out)[i] = make_float2((lo0 - lz) * LN2, (lo1 - lz) * LN2);
}

extern "C" void kernel_launch(void* const* d_in, const int* in_sizes, int n_in,
                              void* d_out, int out_size, void* d_ws, size_t ws_size,
                              hipStream_t stream) {
    const int* corr    = (const int*)d_in[0];
    const int* kc      = (const int*)d_in[1];
    const float* A     = (const float*)d_in[2];
    const float* trans = (const float*)d_in[3];
    const float* obs   = (const float*)d_in[4];
    const float* init  = (const float*)d_in[5];
    float* out = (float*)d_out;

    float* P = (float*)d_ws;  // K*8 floats = 64 KB (log2 units)

    precompute_P<<<KK, 64, 0, stream>>>(A, trans, obs, P);
    bkt_main<<<BB, 64, 0, stream>>>(corr, kc, A, init, P, out);
    finish_py<<<(BB * TT + 255) / 256, 256, 0, stream>>>(kc, P, out);
}

// Round 6
// 94.552 us; speedup vs baseline: 7.8079x; 1.0857x over previous
//
#include <hip/hip_runtime.h>
#include <math.h>

#define BB 1024
#define TT 500
#define CC_ 64
#define KK 2000

#define LOG2E 1.44269504088896340736f
#define LN2   0.69314718055994530942f

// ---- fast hardware exp2/log2 (v_exp_f32 / v_log_f32) ----
#if __has_builtin(__builtin_amdgcn_exp2f)
__device__ __forceinline__ float fast_exp2(float x) { return __builtin_amdgcn_exp2f(x); }
#else
__device__ __forceinline__ float fast_exp2(float x) { return exp2f(x); }
#endif
#if __has_builtin(__builtin_amdgcn_logf)
__device__ __forceinline__ float fast_log2(float x) { return __builtin_amdgcn_logf(x); }
#else
__device__ __forceinline__ float fast_log2(float x) { return log2f(x); }
#endif

// max-guarded log2-sum-exp2 (off the hot loop)
__device__ __forceinline__ float lse2_2(float a, float b) {
    float m = fmaxf(a, b);
    float d = fminf(a, b) - m;              // <= 0
    return m + fast_log2(1.0f + fast_exp2(d));
}

// ---- DPP adds (VALU pipe, no LDS) ----
template<int CTRL, int RM, int BM>
__device__ __forceinline__ float dpp_add(float x) {
    int s = __builtin_amdgcn_update_dpp(0, __float_as_int(x), CTRL, RM, BM, true);
    return x + __int_as_float(s);
}
// full 64-lane sum into lane 63 (precompute only)
__device__ __forceinline__ float wave_sum63(float x) {
    x = dpp_add<0x111, 0xf, 0xf>(x);  // row_shr:1
    x = dpp_add<0x112, 0xf, 0xf>(x);  // row_shr:2
    x = dpp_add<0x114, 0xf, 0xf>(x);  // row_shr:4
    x = dpp_add<0x118, 0xf, 0xf>(x);  // row_shr:8
    x = dpp_add<0x142, 0xa, 0xf>(x);  // row_bcast15 (rows 1,3)
    x = dpp_add<0x143, 0xc, 0xf>(x);  // row_bcast31 (rows 2,3)
    return x;
}
// sum over the 16-lane DPP row; result in EVERY lane of the row (rotations)
__device__ __forceinline__ float rowsum16(float x) {
    x = dpp_add<0x121, 0xf, 0xf>(x);  // row_ror:1
    x = dpp_add<0x122, 0xf, 0xf>(x);  // row_ror:2
    x = dpp_add<0x124, 0xf, 0xf>(x);  // row_ror:4
    x = dpp_add<0x128, 0xf, 0xf>(x);  // row_ror:8
    return x;
}

// Precompute per-k tables (log2 units):
//   PA[k]    = {a1[0][0], a1[0][1], a1[1][0], a1[1][1]}         (for finish_py)
//   P3[k][y] = {2^(sel0+q00), 2^(sel0+q10), sel1+q01, sel1+q11} (for bkt_main)
// where a1[s][o] = sum_c A[k,c]*log2_softmax(obs)[c,s,o], sel_s = a1[s][y],
//       q[s][u]  = sum_c A[k,c]*log2_softmax_ax1(trans)[c,s,u]
__global__ __launch_bounds__(64) void precompute_P(
    const float* __restrict__ A,
    const float* __restrict__ trans_logits,
    const float* __restrict__ obs_logits,
    float* __restrict__ PA,
    float* __restrict__ P3)
{
    int k = blockIdx.x;
    int c = threadIdx.x;  // 0..63

    float ob[2][2];
#pragma unroll
    for (int s = 0; s < 2; ++s) {
        float o0 = obs_logits[c * 4 + s * 2 + 0] * LOG2E;
        float o1 = obs_logits[c * 4 + s * 2 + 1] * LOG2E;
        float l = lse2_2(o0, o1);
        ob[s][0] = o0 - l;
        ob[s][1] = o1 - l;
    }
    float lt[2][2];
    {
        float t00 = trans_logits[c * 4 + 0] * LOG2E;
        float t01 = trans_logits[c * 4 + 1] * LOG2E;
        float t10 = trans_logits[c * 4 + 2] * LOG2E;
        float t11 = trans_logits[c * 4 + 3] * LOG2E;
        float l0 = lse2_2(t00, t10);  // normalize over s (axis=1), u=0
        float l1 = lse2_2(t01, t11);  // u=1
        lt[0][0] = t00 - l0; lt[0][1] = t01 - l1;
        lt[1][0] = t10 - l0; lt[1][1] = t11 - l1;
    }

    float a = A[k * CC_ + c];
    float v[8];
    v[0] = a * ob[0][0]; v[1] = a * ob[0][1];
    v[2] = a * ob[1][0]; v[3] = a * ob[1][1];
    v[4] = a * lt[0][0]; v[5] = a * lt[0][1];
    v[6] = a * lt[1][0]; v[7] = a * lt[1][1];

#pragma unroll
    for (int i = 0; i < 8; ++i) v[i] = wave_sum63(v[i]);
    if (c == 63) {
        ((float4*)PA)[k] = make_float4(v[0], v[1], v[2], v[3]);
#pragma unroll
        for (int y = 0; y < 2; ++y) {
            float sel0 = v[y];      // a1[0][y]
            float sel1 = v[2 + y];  // a1[1][y]
            ((float4*)P3)[k * 2 + y] = make_float4(
                fast_exp2(sel0 + v[4]),   // E0 = 2^(sel0+q00)
                fast_exp2(sel0 + v[6]),   // E1 = 2^(sel0+q10)
                sel1 + v[5],              // v0 = sel1+q01
                sel1 + v[7]);             // v1 = sel1+q11
        }
    }
}

// Serial forward pass, 4 batches per wave. Group g = lane>>4 owns batch
// blockIdx*4+g; lane i = lane&15 holds chains 4i..4i+3 (la in 8 VGPRs).
// Reduction: 2 FMA trees + 4 row_ror DPP hops -> full sum in every lane
// (no readlane). Tail uses d = r1-r0 only: a3s' = log2(Es + 2^(vs+d)) with
// Es, vs from the P3 table (y folded into the address). Renorm by -r0 per
// step keeps ranges safe (uniform shift, output-invariant). All in-loop
// loads are per-lane VMEM (partially-waitable vmcnt), ringed ahead.
__global__ __launch_bounds__(64) void bkt_main(
    const int* __restrict__ corr,
    const int* __restrict__ kc,
    const float* __restrict__ A,
    const float* __restrict__ init_logits,
    const float* __restrict__ P3,
    float* __restrict__ out)
{
    int lane = threadIdx.x;
    int g = lane >> 4, i = lane & 15;
    int b = blockIdx.x * 4 + g;

    // la[j][s]: chain c = 4i+j, state s (log2-softmax of init)
    float la[4][2];
#pragma unroll
    for (int j = 0; j < 4; ++j) {
        float i0 = init_logits[(4 * i + j) * 2 + 0] * LOG2E;
        float i1 = init_logits[(4 * i + j) * 2 + 1] * LOG2E;
        float l = lse2_2(i0, i1);
        la[j][0] = i0 - l;
        la[j][1] = i1 - l;
    }

    const int* kcb = kc + b * TT;
    const int* cb  = corr + b * TT;
    float2* outb   = (float2*)(out + (size_t)b * TT * 2);

    // k/y ring, depth 8
    int kq[8], yq[8];
#pragma unroll
    for (int q = 0; q < 8; ++q) { kq[q] = kcb[q]; yq[q] = cb[q]; }

    // A-row / P3-row rings, depth 4; prefill t=0,1,2
    float4 ccq[4], pq[4];
#pragma unroll
    for (int q = 0; q < 3; ++q) {
        ccq[q] = *(const float4*)(A + kq[q] * CC_ + 4 * i);
        pq[q]  = ((const float4*)P3)[kq[q] * 2 + yq[q]];
    }

    // 63 blocks of 8 = 504 steps; t=500..503 are phantoms (clamped loads,
    // guarded store, discarded la updates on valid-but-stale data).
    for (int tt = 0; tt <= 496; tt += 8) {
#pragma unroll
        for (int j = 0; j < 8; ++j) {
            int t = tt + j;
            // refill k/y slot j with step t+8 (clamped: no OOB)
            int t8 = t + 8; if (t8 > TT - 1) t8 = TT - 1;
            int knew = kcb[t8];
            int ynew = cb[t8];
            // prefetch A/P3 for step t+3
            int kp = kq[(j + 3) & 7], yp = yq[(j + 3) & 7];
            ccq[(j + 3) & 3] = *(const float4*)(A + kp * CC_ + 4 * i);
            pq[(j + 3) & 3]  = ((const float4*)P3)[kp * 2 + yp];

            float4 cc = ccq[j & 3];
            float4 pr = pq[j & 3];
            kq[j] = knew; yq[j] = ynew;

            // r[s] = sum_c A[k,c]*la[c,s]: in-lane tree + 4 DPP rors
            float x0 = (cc.x * la[0][0] + cc.y * la[1][0])
                     + (cc.z * la[2][0] + cc.w * la[3][0]);
            float x1 = (cc.x * la[0][1] + cc.y * la[1][1])
                     + (cc.z * la[2][1] + cc.w * la[3][1]);
            x0 = rowsum16(x0);
            x1 = rowsum16(x1);
            if (t < TT && i == 0) outb[t] = make_float2(x0, x1);

            // tail: only d = r1-r0 enters; E/v precomputed per (k,y)
            float d   = x1 - x0;
            float a30 = fast_log2(pr.x + fast_exp2(pr.z + d));  // a3[0]-r0
            float a31 = fast_log2(pr.y + fast_exp2(pr.w + d));  // a3[1]-r0
            // la_new = (1-cc)*(la - r0) + cc*a3'  (renorm by -r0 built in)
            {
                float g0, g1;
                g0 = la[0][0] - x0; g1 = la[0][1] - x0;
                la[0][0] = g0 + cc.x * (a30 - g0);
                la[0][1] = g1 + cc.x * (a31 - g1);
                g0 = la[1][0] - x0; g1 = la[1][1] - x0;
                la[1][0] = g0 + cc.y * (a30 - g0);
                la[1][1] = g1 + cc.y * (a31 - g1);
                g0 = la[2][0] - x0; g1 = la[2][1] - x0;
                la[2][0] = g0 + cc.z * (a30 - g0);
                la[2][1] = g1 + cc.z * (a31 - g1);
                g0 = la[3][0] - x0; g1 = la[3][1] - x0;
                la[3][0] = g0 + cc.w * (a30 - g0);
                la[3][1] = g1 + cc.w * (a31 - g1);
            }
        }
    }
}

// Fully parallel epilogue: stored (r0,r1) -> log-softmax'd output (nat-log).
__global__ __launch_bounds__(256) void finish_py(
    const int* __restrict__ kc,
    const float* __restrict__ PA,
    float* __restrict__ out)
{
    int idx = blockIdx.x * 256 + threadIdx.x;  // idx = b*TT + t
    if (idx >= BB * TT) return;
    int k = kc[idx];
    float2 r  = ((const float2*)out)[idx];
    float4 pa = ((const float4*)PA)[k];
    float lo0 = lse2_2(pa.x + r.x, pa.z + r.y);  // log2 p(y=0) (shifted)
    float lo1 = lse2_2(pa.y + r.x, pa.w + r.y);  // log2 p(y=1) (shifted)
    float lz  = lse2_2(lo0, lo1);
    ((float2*)out)[idx] = make_float2((lo0 - lz) * LN2, (lo1 - lz) * LN2);
}

extern "C" void kernel_launch(void* const* d_in, const int* in_sizes, int n_in,
                              void* d_out, int out_size, void* d_ws, size_t ws_size,
                              hipStream_t stream) {
    const int* corr    = (const int*)d_in[0];
    const int* kc      = (const int*)d_in[1];
    const float* A     = (const float*)d_in[2];
    const float* trans = (const float*)d_in[3];
    const float* obs   = (const float*)d_in[4];
    const float* init  = (const float*)d_in[5];
    float* out = (float*)d_out;

    float* PA = (float*)d_ws;          // K*4 floats = 32 KB
    float* P3 = PA + KK * 4;           // K*2*4 floats = 64 KB (total 96 KB)

    precompute_P<<<KK, 64, 0, stream>>>(A, trans, obs, PA, P3);
    bkt_main<<<BB / 4, 64, 0, stream>>>(corr, kc, A, init, P3, out);
    finish_py<<<(BB * TT + 255) / 256, 256, 0, stream>>>(kc, PA, out);
}